// Round 3
// baseline (2316.933 us; speedup 1.0000x reference)
//
#include <hip/hip_runtime.h>
#include <hip/hip_bf16.h>

// CNF: hypernet(t) -> (W,B,U) per time; RK4 integrate z (N=65536, D=8) and logp.
// R2 -> R3 change: params staged into LDS per half-segment (5 slots, 46 KB)
// with coalesced vector loads; hot loop reads via broadcast ds_read instead of
// serialized scalar loads (which caused 62% stall at 1 wave/SIMD).

#define DD 8
#define HIDDEN 64
#define WIDTH 128
#define NSAMP 65536
#define TT 8
#define PSTRIDE 2304   // floats per slot: 128*16 rows + 128*2 (B, dotWU)
#define NSLOT 63       // 7 segments * 9 distinct times

__device__ __forceinline__ float tanh_fast(float x) {
    float e = __builtin_amdgcn_exp2f(x * 2.88539008177792681472f);
    float r = __builtin_amdgcn_rcpf(e + 1.0f);
    return __builtin_fmaf(-2.0f, r, 1.0f);
}

__device__ __forceinline__ float sigmoid_fast(float x) {
    float e = __builtin_amdgcn_exp2f(x * -1.44269504088896340736f);
    return __builtin_amdgcn_rcpf(e + 1.0f);
}

__global__ __launch_bounds__(256) void cnf_hyper(
    const float* __restrict__ ts,
    const float* __restrict__ w1,
    const float* __restrict__ b1,
    const float* __restrict__ w2,
    const float* __restrict__ b2,
    const float* __restrict__ w3,
    const float* __restrict__ b3,
    float* __restrict__ params)
{
    const int slot = blockIdx.x;          // 0..62
    const int seg = slot / 9;
    const int j = slot % 9;
    const float t0 = ts[seg];
    const float t1 = ts[seg + 1];
    const float dt = (t1 - t0) * 0.25f;
    float t = t0;
    const int na = (j < 4) ? j : ((j < 8) ? (j - 4) : 4);
    for (int i = 0; i < na; ++i) t += dt;
    if (j >= 4 && j < 8) t += dt * 0.5f;

    __shared__ float h1s[HIDDEN];
    __shared__ float h2s[HIDDEN];
    __shared__ float pbuf[3 * WIDTH * DD + WIDTH];  // 3200

    const int tid = threadIdx.x;
    if (tid < HIDDEN) {
        h1s[tid] = tanh_fast(__builtin_fmaf(w1[tid], t, b1[tid]));
    }
    __syncthreads();
    if (tid < HIDDEN) {
        float a = b2[tid];
        #pragma unroll 8
        for (int k = 0; k < HIDDEN; ++k)
            a = __builtin_fmaf(w2[tid * HIDDEN + k], h1s[k], a);
        h2s[tid] = tanh_fast(a);
    }
    __syncthreads();
    for (int r = tid; r < 3200; r += 256) {
        float a = b3[r];
        const float* wr = w3 + (size_t)r * HIDDEN;
        #pragma unroll 8
        for (int k = 0; k < HIDDEN; ++k)
            a = __builtin_fmaf(wr[k], h2s[k], a);
        pbuf[r] = a;
    }
    __syncthreads();
    if (tid < WIDTH) {
        const int w = tid;
        float* dst = params + (size_t)slot * PSTRIDE + w * 16;
        float dot = 0.0f;
        #pragma unroll
        for (int d = 0; d < DD; ++d) {
            float Wd = pbuf[w * DD + d];
            float Ud = pbuf[WIDTH * DD + w * DD + d] *
                       sigmoid_fast(pbuf[2 * WIDTH * DD + w * DD + d]);
            dst[d] = Wd;
            dst[8 + d] = Ud;
            dot = __builtin_fmaf(Wd, Ud, dot);
        }
        float* bd = params + (size_t)slot * PSTRIDE + 2048;
        bd[2 * w] = pbuf[3 * WIDTH * DD + w];
        bd[2 * w + 1] = dot;
    }
}

// p points into LDS (slot base). Wave-uniform addresses -> broadcast ds_read.
__device__ __forceinline__ void rhs_eval(const float* p,
                                         const float z[DD], float f[DD], float* kl)
{
    #pragma unroll
    for (int d = 0; d < DD; ++d) f[d] = 0.0f;
    float tr = 0.0f;
    const float* bd = p + 2048;
    #pragma unroll 8
    for (int w = 0; w < WIDTH; ++w) {
        const float* row = p + w * 16;
        float a = bd[2 * w];
        #pragma unroll
        for (int d = 0; d < DD; ++d) a = __builtin_fmaf(row[d], z[d], a);
        float th = tanh_fast(a);
        #pragma unroll
        for (int d = 0; d < DD; ++d) f[d] = __builtin_fmaf(th, row[8 + d], f[d]);
        tr = __builtin_fmaf(__builtin_fmaf(-th, th, 1.0f), bd[2 * w + 1], tr);
    }
    const float inv = 1.0f / (float)WIDTH;
    #pragma unroll
    for (int d = 0; d < DD; ++d) f[d] *= inv;
    *kl = -tr * inv;
}

__global__ __launch_bounds__(256) void cnf_integrate(
    const float* __restrict__ ts,
    const float* __restrict__ z0,
    const float* __restrict__ lp0,
    const float* __restrict__ params,
    float* __restrict__ out)
{
    const int n = blockIdx.x * 256 + threadIdx.x;
    const int tid = threadIdx.x;
    const size_t LPBASE = (size_t)TT * NSAMP * DD;  // 4194304

    // 5 param slots staged per half-segment: 5 * 2304 floats = 46080 B LDS
    __shared__ float spar[5 * PSTRIDE];

    float z[DD], acc[DD], zin[DD], f[DD];
    #pragma unroll
    for (int d = 0; d < DD; ++d) z[d] = z0[(size_t)n * DD + d];
    float lp = lp0[n];

    #pragma unroll
    for (int d = 0; d < DD; ++d) out[(size_t)n * DD + d] = z[d];
    out[LPBASE + n] = lp;

    // half h slot lists (global slot id within segment) and per-stage LDS slot idx
    // half0 slots {0,1,2,4,5}: stage0 (a,b,c)=(ls0,ls3,ls1); stage1 (ls1,ls4,ls2)
    // half1 slots {2,3,6,7,8}: stage2 (a,b,c)=(ls0,ls2,ls1); stage3 (ls1,ls3,ls4)
    const int slotlist[2][5] = { {0, 1, 2, 4, 5}, {2, 3, 6, 7, 8} };
    const int stageidx[4][3] = { {0, 3, 1}, {1, 4, 2}, {0, 2, 1}, {1, 3, 4} };

    for (int seg = 0; seg < TT - 1; ++seg) {
        const float t0 = ts[seg];
        const float t1 = ts[seg + 1];
        const float dt = (t1 - t0) * 0.25f;
        const float c6 = dt * (1.0f / 6.0f);
        const float c3 = dt * (1.0f / 3.0f);
        const float h2 = dt * 0.5f;
        const float* segp = params + (size_t)seg * 9 * PSTRIDE;

        for (int h = 0; h < 2; ++h) {
            // ---- stage 5 slots into LDS with coalesced float4 loads ----
            __syncthreads();   // prior readers done before overwrite
            for (int sl = 0; sl < 5; ++sl) {
                const float4* src = (const float4*)(segp + (size_t)slotlist[h][sl] * PSTRIDE);
                float4* dst = (float4*)(spar + sl * PSTRIDE);
                #pragma unroll
                for (int c = tid; c < PSTRIDE / 4; c += 256)  // 576 chunks
                    dst[c] = src[c];
            }
            __syncthreads();

            for (int ss = 0; ss < 2; ++ss) {
                const int s = h * 2 + ss;
                const float* pa = spar + stageidx[s][0] * PSTRIDE;
                const float* pb = spar + stageidx[s][1] * PSTRIDE;
                const float* pc = spar + stageidx[s][2] * PSTRIDE;
                float kl, lacc;
                // k1
                rhs_eval(pa, z, f, &kl);
                #pragma unroll
                for (int d = 0; d < DD; ++d) {
                    acc[d] = __builtin_fmaf(c6, f[d], z[d]);
                    zin[d] = __builtin_fmaf(h2, f[d], z[d]);
                }
                lacc = __builtin_fmaf(c6, kl, lp);
                // k2
                rhs_eval(pb, zin, f, &kl);
                #pragma unroll
                for (int d = 0; d < DD; ++d) {
                    acc[d] = __builtin_fmaf(c3, f[d], acc[d]);
                    zin[d] = __builtin_fmaf(h2, f[d], z[d]);
                }
                lacc = __builtin_fmaf(c3, kl, lacc);
                // k3
                rhs_eval(pb, zin, f, &kl);
                #pragma unroll
                for (int d = 0; d < DD; ++d) {
                    acc[d] = __builtin_fmaf(c3, f[d], acc[d]);
                    zin[d] = __builtin_fmaf(dt, f[d], z[d]);
                }
                lacc = __builtin_fmaf(c3, kl, lacc);
                // k4
                rhs_eval(pc, zin, f, &kl);
                #pragma unroll
                for (int d = 0; d < DD; ++d)
                    z[d] = __builtin_fmaf(c6, f[d], acc[d]);
                lp = __builtin_fmaf(c6, kl, lacc);
            }
        }
        const size_t zo = (size_t)(seg + 1) * NSAMP * DD + (size_t)n * DD;
        #pragma unroll
        for (int d = 0; d < DD; ++d) out[zo + d] = z[d];
        out[LPBASE + (size_t)(seg + 1) * NSAMP + n] = lp;
    }
}

extern "C" void kernel_launch(void* const* d_in, const int* in_sizes, int n_in,
                              void* d_out, int out_size, void* d_ws, size_t ws_size,
                              hipStream_t stream) {
    const float* ts  = (const float*)d_in[0];
    const float* z0  = (const float*)d_in[1];
    const float* lp0 = (const float*)d_in[2];
    const float* w1  = (const float*)d_in[3];
    const float* b1  = (const float*)d_in[4];
    const float* w2  = (const float*)d_in[5];
    const float* b2  = (const float*)d_in[6];
    const float* w3  = (const float*)d_in[7];
    const float* b3  = (const float*)d_in[8];
    float* params = (float*)d_ws;  // 63 * 2304 * 4 B = 580,608 B

    cnf_hyper<<<dim3(NSLOT), dim3(256), 0, stream>>>(ts, w1, b1, w2, b2, w3, b3, params);
    cnf_integrate<<<dim3(NSAMP / 256), dim3(256), 0, stream>>>(
        ts, z0, lp0, params, (float*)d_out);
}

// Round 4
// 795.323 us; speedup vs baseline: 2.9132x; 2.9132x over previous
//
#include <hip/hip_runtime.h>

// CNF: hypernet(t) -> 63 param slots; RK4 integrate z (N=65536, D=8) + logp.
// R4: 4 threads/sample (262144 threads, 4 waves/SIMD) + shfl_xor butterfly;
// params double-buffered in LDS (2x10240B), staged via register prefetch,
// rows padded to 20 floats + mod-4 interleave => conflict-free ds_read_b128.

#define DD 8
#define HIDDEN 64
#define WIDTH 128
#define NSAMP 65536
#define TT 8
#define RSTRIDE 20                      // floats per row: W8 U8 B dot pad2
#define SLOTF (WIDTH * RSTRIDE)         // 2560 floats = 10240 B per slot
#define NSLOT 63                        // 7 segments * 9 distinct times
#define TSPL 4                          // threads per sample
#define RPT (WIDTH / TSPL)              // 32 rows per thread

__device__ __forceinline__ float tanh_fast(float x) {
    float e = __builtin_amdgcn_exp2f(x * 2.88539008177792681472f);
    float r = __builtin_amdgcn_rcpf(e + 1.0f);
    return __builtin_fmaf(-2.0f, r, 1.0f);
}

__device__ __forceinline__ float sigmoid_fast(float x) {
    float e = __builtin_amdgcn_exp2f(x * -1.44269504088896340736f);
    return __builtin_amdgcn_rcpf(e + 1.0f);
}

__global__ __launch_bounds__(256) void cnf_hyper(
    const float* __restrict__ ts,
    const float* __restrict__ w1,
    const float* __restrict__ b1,
    const float* __restrict__ w2,
    const float* __restrict__ b2,
    const float* __restrict__ w3,
    const float* __restrict__ b3,
    float* __restrict__ params)
{
    const int slot = blockIdx.x;          // 0..62
    const int seg = slot / 9;
    const int j = slot % 9;
    const float t0 = ts[seg];
    const float t1 = ts[seg + 1];
    const float dt = (t1 - t0) * 0.25f;
    float t = t0;                          // replicate reference's accumulated chain
    const int na = (j < 4) ? j : ((j < 8) ? (j - 4) : 4);
    for (int i = 0; i < na; ++i) t += dt;
    if (j >= 4 && j < 8) t += dt * 0.5f;

    __shared__ float h1s[HIDDEN];
    __shared__ float h2s[HIDDEN];
    __shared__ float pbuf[3 * WIDTH * DD + WIDTH];  // 3200

    const int tid = threadIdx.x;
    if (tid < HIDDEN) {
        h1s[tid] = tanh_fast(__builtin_fmaf(w1[tid], t, b1[tid]));
    }
    __syncthreads();
    if (tid < HIDDEN) {
        float a = b2[tid];
        #pragma unroll 8
        for (int k = 0; k < HIDDEN; ++k)
            a = __builtin_fmaf(w2[tid * HIDDEN + k], h1s[k], a);
        h2s[tid] = tanh_fast(a);
    }
    __syncthreads();
    for (int r = tid; r < 3200; r += 256) {
        float a = b3[r];
        const float* wr = w3 + (size_t)r * HIDDEN;
        #pragma unroll 8
        for (int k = 0; k < HIDDEN; ++k)
            a = __builtin_fmaf(wr[k], h2s[k], a);
        pbuf[r] = a;
    }
    __syncthreads();
    if (tid < WIDTH) {
        const int w = tid;
        float* dst = params + (size_t)slot * SLOTF + w * RSTRIDE;
        float dot = 0.0f;
        #pragma unroll
        for (int d = 0; d < DD; ++d) {
            float Wd = pbuf[w * DD + d];
            float Ud = pbuf[WIDTH * DD + w * DD + d] *
                       sigmoid_fast(pbuf[2 * WIDTH * DD + w * DD + d]);
            dst[d] = Wd;
            dst[8 + d] = Ud;
            dot = __builtin_fmaf(Wd, Ud, dot);
        }
        dst[16] = pbuf[3 * WIDTH * DD + w];  // B
        dst[17] = dot;
        dst[18] = 0.0f;
        dst[19] = 0.0f;
    }
}

__global__ __launch_bounds__(256, 4) void cnf_integrate(
    const float* __restrict__ ts,
    const float* __restrict__ z0,
    const float* __restrict__ lp0,
    const float* __restrict__ params,
    float* __restrict__ out)
{
    const int tid = threadIdx.x;
    const int widx = tid & (TSPL - 1);
    const int n = blockIdx.x * 64 + (tid >> 2);
    const size_t LPBASE = (size_t)TT * NSAMP * DD;  // 4194304

    __shared__ float spar[2][SLOTF];    // 2 x 10240 B

    float z[DD], acc[DD], zin[DD], f[DD];
    {
        const float4* zsrc = (const float4*)(z0 + (size_t)n * DD);
        float4 a = zsrc[0], b = zsrc[1];
        z[0]=a.x; z[1]=a.y; z[2]=a.z; z[3]=a.w;
        z[4]=b.x; z[5]=b.y; z[6]=b.z; z[7]=b.w;
    }
    float lp = lp0[n];

    if (widx == 0) {
        float4* zo = (float4*)(out + (size_t)n * DD);
        zo[0] = make_float4(z[0], z[1], z[2], z[3]);
        zo[1] = make_float4(z[4], z[5], z[6], z[7]);
        out[LPBASE + n] = lp;
    }

    const int dorder[9] = {0, 4, 1, 5, 2, 6, 3, 7, 8};  // distinct-slot order/seg

    float4 r0, r1, r2 = make_float4(0.f, 0.f, 0.f, 0.f);

    auto stage_regs = [&](int pidx) {
        const int gid = (pidx / 9) * 9 + dorder[pidx % 9];
        const float4* s4 = (const float4*)(params + (size_t)gid * SLOTF);
        r0 = s4[tid];
        r1 = s4[tid + 256];
        if (tid < 128) r2 = s4[tid + 512];
    };
    auto flush_regs = [&](float* dst) {
        float4* d4 = (float4*)dst;
        d4[tid] = r0;
        d4[tid + 256] = r1;
        if (tid < 128) d4[tid + 512] = r2;
    };

    int par = 0;
    int pidx = 1;
    stage_regs(0);
    flush_regs(spar[0]);
    __syncthreads();
    stage_regs(1);   // prefetch next slot into regs

    auto advance = [&]() {
        flush_regs(spar[par ^ 1]);
        __syncthreads();
        par ^= 1;
        ++pidx;
        if (pidx < NSLOT) stage_regs(pidx);
    };

    float lacc = 0.0f;
    const float inv = 1.0f / (float)WIDTH;

    for (int seg = 0; seg < TT - 1; ++seg) {
        if (seg > 0) advance();
        const float t0 = ts[seg], t1 = ts[seg + 1];
        const float dt = (t1 - t0) * 0.25f;
        const float c6 = dt * (1.0f / 6.0f);
        const float c3 = dt * (1.0f / 3.0f);
        const float h2 = dt * 0.5f;

        #pragma unroll 1
        for (int r = 0; r < 16; ++r) {
            if (r & 1) advance();
            const int k = r & 3;
            if (k == 0) {
                #pragma unroll
                for (int d = 0; d < DD; ++d) zin[d] = z[d];
            }
            // ---- rhs_eval on zin: rows widx, widx+4, ... (conflict-free) ----
            #pragma unroll
            for (int d = 0; d < DD; ++d) f[d] = 0.0f;
            float tr = 0.0f;
            const float* sp = spar[par];
            #pragma unroll 2
            for (int j = 0; j < RPT; ++j) {
                const float* row = sp + (widx + TSPL * j) * RSTRIDE;
                const float4 w0 = *(const float4*)(row);
                const float4 w1v = *(const float4*)(row + 4);
                const float4 u0 = *(const float4*)(row + 8);
                const float4 u1 = *(const float4*)(row + 12);
                const float2 bd = *(const float2*)(row + 16);
                float a = bd.x;
                a = __builtin_fmaf(w0.x, zin[0], a);
                a = __builtin_fmaf(w0.y, zin[1], a);
                a = __builtin_fmaf(w0.z, zin[2], a);
                a = __builtin_fmaf(w0.w, zin[3], a);
                a = __builtin_fmaf(w1v.x, zin[4], a);
                a = __builtin_fmaf(w1v.y, zin[5], a);
                a = __builtin_fmaf(w1v.z, zin[6], a);
                a = __builtin_fmaf(w1v.w, zin[7], a);
                const float th = tanh_fast(a);
                f[0] = __builtin_fmaf(th, u0.x, f[0]);
                f[1] = __builtin_fmaf(th, u0.y, f[1]);
                f[2] = __builtin_fmaf(th, u0.z, f[2]);
                f[3] = __builtin_fmaf(th, u0.w, f[3]);
                f[4] = __builtin_fmaf(th, u1.x, f[4]);
                f[5] = __builtin_fmaf(th, u1.y, f[5]);
                f[6] = __builtin_fmaf(th, u1.z, f[6]);
                f[7] = __builtin_fmaf(th, u1.w, f[7]);
                tr = __builtin_fmaf(__builtin_fmaf(-th, th, 1.0f), bd.y, tr);
            }
            // butterfly over the 4 widx lanes (same sample: masks 1,2)
            #pragma unroll
            for (int m = 1; m <= 2; m <<= 1) {
                #pragma unroll
                for (int d = 0; d < DD; ++d) f[d] += __shfl_xor(f[d], m, 64);
                tr += __shfl_xor(tr, m, 64);
            }
            #pragma unroll
            for (int d = 0; d < DD; ++d) f[d] *= inv;
            const float kl = -tr * inv;
            // ---- RK4 update (uniform branch on k) ----
            if (k == 0) {
                #pragma unroll
                for (int d = 0; d < DD; ++d) {
                    acc[d] = __builtin_fmaf(c6, f[d], z[d]);
                    zin[d] = __builtin_fmaf(h2, f[d], z[d]);
                }
                lacc = __builtin_fmaf(c6, kl, lp);
            } else if (k == 1) {
                #pragma unroll
                for (int d = 0; d < DD; ++d) {
                    acc[d] = __builtin_fmaf(c3, f[d], acc[d]);
                    zin[d] = __builtin_fmaf(h2, f[d], z[d]);
                }
                lacc = __builtin_fmaf(c3, kl, lacc);
            } else if (k == 2) {
                #pragma unroll
                for (int d = 0; d < DD; ++d) {
                    acc[d] = __builtin_fmaf(c3, f[d], acc[d]);
                    zin[d] = __builtin_fmaf(dt, f[d], z[d]);
                }
                lacc = __builtin_fmaf(c3, kl, lacc);
            } else {
                #pragma unroll
                for (int d = 0; d < DD; ++d)
                    z[d] = __builtin_fmaf(c6, f[d], acc[d]);
                lp = __builtin_fmaf(c6, kl, lacc);
            }
        }
        if (widx == 0) {
            float* zo = out + (size_t)(seg + 1) * NSAMP * DD + (size_t)n * DD;
            ((float4*)zo)[0] = make_float4(z[0], z[1], z[2], z[3]);
            ((float4*)zo)[1] = make_float4(z[4], z[5], z[6], z[7]);
            out[LPBASE + (size_t)(seg + 1) * NSAMP + n] = lp;
        }
    }
}

extern "C" void kernel_launch(void* const* d_in, const int* in_sizes, int n_in,
                              void* d_out, int out_size, void* d_ws, size_t ws_size,
                              hipStream_t stream) {
    const float* ts  = (const float*)d_in[0];
    const float* z0  = (const float*)d_in[1];
    const float* lp0 = (const float*)d_in[2];
    const float* w1  = (const float*)d_in[3];
    const float* b1  = (const float*)d_in[4];
    const float* w2  = (const float*)d_in[5];
    const float* b2  = (const float*)d_in[6];
    const float* w3  = (const float*)d_in[7];
    const float* b3  = (const float*)d_in[8];
    float* params = (float*)d_ws;  // 63 * 2560 * 4 B = 645,120 B

    cnf_hyper<<<dim3(NSLOT), dim3(256), 0, stream>>>(ts, w1, b1, w2, b2, w3, b3, params);
    cnf_integrate<<<dim3(NSAMP * TSPL / 256), dim3(256), 0, stream>>>(
        ts, z0, lp0, params, (float*)d_out);
}

// Round 6
// 573.392 us; speedup vs baseline: 4.0407x; 1.3870x over previous
//
#include <hip/hip_runtime.h>

// CNF via MFMA: hypernet(t) -> 63 f16 fragment slots; RK4 integrate z (N=65536,
// D=8) + logp. One wave = 16 samples. Per rhs: GEMM1 a=W.z+B (8x 16x16x16f16,
// bias folded as K=8 row with z-frag k=8 == 1.0), tanh in-register (C-layout of
// GEMM1 == B-frag layout of K=16 MFMA), GEMM2a f=(U/128).th, GEMM2b
// kl=(-dot/32).(r-r^2). z stays sharded per-lane; no LDS, no barriers, no
// shuffles in the hot loop.

#define DD 8
#define HIDDEN 64
#define WIDTH 128
#define NSAMP 65536
#define TT 8
#define SLOTH 4352          // halves per slot (8704 B): Wf 2048 | Uf 2048 | Df 128 | pad
#define UOFF 2048
#define DOFF 4096
#define NSLOT 63            // 7 segments * 9 distinct times

typedef __fp16 half4 __attribute__((ext_vector_type(4)));
typedef __fp16 half2t __attribute__((ext_vector_type(2)));
typedef float float4v __attribute__((ext_vector_type(4)));

__device__ __forceinline__ float tanh_fast(float x) {
    float e = __builtin_amdgcn_exp2f(x * 2.88539008177792681472f);
    float r = __builtin_amdgcn_rcpf(e + 1.0f);
    return __builtin_fmaf(-2.0f, r, 1.0f);
}

__device__ __forceinline__ float sigmoid_fast(float x) {
    float e = __builtin_amdgcn_exp2f(x * -1.44269504088896340736f);
    return __builtin_amdgcn_rcpf(e + 1.0f);
}

__global__ __launch_bounds__(256) void cnf_hyper(
    const float* __restrict__ ts,
    const float* __restrict__ w1,
    const float* __restrict__ b1,
    const float* __restrict__ w2,
    const float* __restrict__ b2,
    const float* __restrict__ w3,
    const float* __restrict__ b3,
    __fp16* __restrict__ params)
{
    const int slot = blockIdx.x;          // 0..62
    const int seg = slot / 9;
    const int j = slot % 9;
    const float t0 = ts[seg];
    const float t1 = ts[seg + 1];
    const float dt = (t1 - t0) * 0.25f;
    float t = t0;                          // replicate reference's accumulated chain
    const int na = (j < 4) ? j : ((j < 8) ? (j - 4) : 4);
    for (int i = 0; i < na; ++i) t += dt;
    if (j >= 4 && j < 8) t += dt * 0.5f;

    __shared__ float h1s[HIDDEN];
    __shared__ float h2s[HIDDEN];
    __shared__ float pbuf[3 * WIDTH * DD + WIDTH];  // 3200

    const int tid = threadIdx.x;
    if (tid < HIDDEN) {
        h1s[tid] = tanh_fast(__builtin_fmaf(w1[tid], t, b1[tid]));
    }
    __syncthreads();
    if (tid < HIDDEN) {
        float a = b2[tid];
        #pragma unroll 8
        for (int k = 0; k < HIDDEN; ++k)
            a = __builtin_fmaf(w2[tid * HIDDEN + k], h1s[k], a);
        h2s[tid] = tanh_fast(a);
    }
    __syncthreads();
    for (int r = tid; r < 3200; r += 256) {
        float a = b3[r];
        const float* wr = w3 + (size_t)r * HIDDEN;
        #pragma unroll 8
        for (int k = 0; k < HIDDEN; ++k)
            a = __builtin_fmaf(wr[k], h2s[k], a);
        pbuf[r] = a;
    }
    __syncthreads();
    if (tid < WIDTH) {
        const int w = tid;
        __fp16* dst = params + (size_t)slot * SLOTH;
        float dot = 0.0f;
        #pragma unroll
        for (int d = 0; d < DD; ++d) {
            float Wd = pbuf[w * DD + d];
            float Ud = pbuf[WIDTH * DD + w * DD + d] *
                       sigmoid_fast(pbuf[2 * WIDTH * DD + w * DD + d]);
            dst[w * 16 + d] = (__fp16)Wd;                       // A-frag GEMM1 row w
            dst[UOFF + d * 128 + w] = (__fp16)(Ud * (1.0f / 128.0f)); // A-frag GEMM2a row d
            dot = __builtin_fmaf(Wd, Ud, dot);
        }
        dst[w * 16 + 8] = (__fp16)pbuf[3 * WIDTH * DD + w];     // bias at k=8
        #pragma unroll
        for (int kk = 9; kk < 16; ++kk) dst[w * 16 + kk] = (__fp16)0.0f;
        #pragma unroll
        for (int m = DD; m < 16; ++m) dst[UOFF + m * 128 + w] = (__fp16)0.0f;
        dst[DOFF + w] = (__fp16)(-dot * (1.0f / 32.0f));        // trace row, scales folded
    }
}

__global__ __launch_bounds__(256, 4) void cnf_integrate(
    const float* __restrict__ ts,
    const float* __restrict__ z0,
    const float* __restrict__ lp0,
    const __fp16* __restrict__ params,
    float* __restrict__ out)
{
    const int lane = threadIdx.x & 63;
    const int wv = threadIdx.x >> 6;
    const int s16 = lane & 15;           // sample col within wave tile
    const int q = lane >> 4;             // quad
    const int n = blockIdx.x * 64 + wv * 16 + s16;
    const size_t LPBASE = (size_t)TT * NSAMP * DD;  // 4194304

    // per-lane element offsets into a slot (halves)
    const int offW = s16 * 16 + q * 4;          // + t*256
    const int offU = UOFF + s16 * 128 + q * 4;  // + t*16
    const int offD = DOFF + q * 4;              // + t*16

    // z shard: q=0 -> z[0..3], q=1 -> z[4..7], q=2 -> (1,0,0,0) bias row, q=3 -> 0
    float zsh[4];
    {
        const float4* zp = (const float4*)(z0 + (size_t)n * DD);
        float4 zl = zp[q & 1];
        zsh[0] = zl.x; zsh[1] = zl.y; zsh[2] = zl.z; zsh[3] = zl.w;
        if (q == 2) { zsh[0] = 1.0f; zsh[1] = 0.0f; zsh[2] = 0.0f; zsh[3] = 0.0f; }
        if (q == 3) { zsh[0] = 0.0f; zsh[1] = 0.0f; zsh[2] = 0.0f; zsh[3] = 0.0f; }
    }
    float lp = lp0[n];

    if (q < 2) {
        float4* zo = (float4*)(out + (size_t)n * DD) + q;
        *zo = make_float4(zsh[0], zsh[1], zsh[2], zsh[3]);
    }
    if (q == 0) out[LPBASE + n] = lp;

    const half4 hzero = {(__fp16)0.f, (__fp16)0.f, (__fp16)0.f, (__fp16)0.f};
    const float4v fzero = {0.f, 0.f, 0.f, 0.f};

    // rhs: zi shard -> f shard + kl (kl valid at q==0, reg0)
    auto RHS = [&](const __fp16* P, const float zi[4], float4v& fo, float& kl) {
        half2t zlo = __builtin_amdgcn_cvt_pkrtz(zi[0], zi[1]);
        half2t zhi = __builtin_amdgcn_cvt_pkrtz(zi[2], zi[3]);
        half4 zf; zf[0] = zlo[0]; zf[1] = zlo[1]; zf[2] = zhi[0]; zf[3] = zhi[1];
        float4v acc2 = fzero, acc3 = fzero;
        #pragma unroll
        for (int t = 0; t < 8; ++t) {
            half4 wf = *(const half4*)(P + offW + t * 256);
            float4v a1 = __builtin_amdgcn_mfma_f32_16x16x16f16(wf, zf, fzero, 0, 0, 0);
            float th[4], sv[4];
            #pragma unroll
            for (int i = 0; i < 4; ++i) {
                float e = __builtin_amdgcn_exp2f(a1[i] * 2.88539008177792681472f);
                float r = __builtin_amdgcn_rcpf(e + 1.0f);
                th[i] = __builtin_fmaf(-2.0f, r, 1.0f);
                sv[i] = __builtin_fmaf(-r, r, r);      // r - r^2 = (1-th^2)/4
            }
            half2t h0 = __builtin_amdgcn_cvt_pkrtz(th[0], th[1]);
            half2t h1 = __builtin_amdgcn_cvt_pkrtz(th[2], th[3]);
            half4 hf; hf[0] = h0[0]; hf[1] = h0[1]; hf[2] = h1[0]; hf[3] = h1[1];
            half2t s0 = __builtin_amdgcn_cvt_pkrtz(sv[0], sv[1]);
            half2t s1 = __builtin_amdgcn_cvt_pkrtz(sv[2], sv[3]);
            half4 sf; sf[0] = s0[0]; sf[1] = s0[1]; sf[2] = s1[0]; sf[3] = s1[1];
            half4 uf = *(const half4*)(P + offU + t * 16);
            acc2 = __builtin_amdgcn_mfma_f32_16x16x16f16(uf, hf, acc2, 0, 0, 0);
            half4 df = *(const half4*)(P + offD + t * 16);
            df = s16 ? hzero : df;                     // trace A row nonzero only at m=0
            acc3 = __builtin_amdgcn_mfma_f32_16x16x16f16(df, sf, acc3, 0, 0, 0);
        }
        fo = acc2;       // already /128 (folded into U)
        kl = acc3[0];    // already -tr/128 (folded into D)
    };

    float zin[4], acc[4];
    float lacc = 0.0f;
    float4v f;
    float kl;

    for (int seg = 0; seg < TT - 1; ++seg) {
        const float t0 = ts[seg], t1 = ts[seg + 1];
        const float dt = (t1 - t0) * 0.25f;
        const float c6 = dt * (1.0f / 6.0f);
        const float c3 = dt * (1.0f / 3.0f);
        const float h2 = dt * 0.5f;
        const __fp16* segp = params + (size_t)seg * 9 * SLOTH;

        #pragma unroll 1
        for (int s = 0; s < 4; ++s) {
            const __fp16* Pa = segp + (size_t)s * SLOTH;
            const __fp16* Pb = segp + (size_t)(4 + s) * SLOTH;
            const __fp16* Pc = segp + (size_t)((s < 3) ? (s + 1) : 8) * SLOTH;
            // k1
            RHS(Pa, zsh, f, kl);
            #pragma unroll
            for (int d = 0; d < 4; ++d) {
                acc[d] = __builtin_fmaf(c6, f[d], zsh[d]);
                zin[d] = __builtin_fmaf(h2, f[d], zsh[d]);
            }
            lacc = __builtin_fmaf(c6, kl, lp);
            // k2
            RHS(Pb, zin, f, kl);
            #pragma unroll
            for (int d = 0; d < 4; ++d) {
                acc[d] = __builtin_fmaf(c3, f[d], acc[d]);
                zin[d] = __builtin_fmaf(h2, f[d], zsh[d]);
            }
            lacc = __builtin_fmaf(c3, kl, lacc);
            // k3
            RHS(Pb, zin, f, kl);
            #pragma unroll
            for (int d = 0; d < 4; ++d) {
                acc[d] = __builtin_fmaf(c3, f[d], acc[d]);
                zin[d] = __builtin_fmaf(dt, f[d], zsh[d]);
            }
            lacc = __builtin_fmaf(c3, kl, lacc);
            // k4
            RHS(Pc, zin, f, kl);
            #pragma unroll
            for (int d = 0; d < 4; ++d)
                zsh[d] = __builtin_fmaf(c6, f[d], acc[d]);
            lp = __builtin_fmaf(c6, kl, lacc);
        }
        if (q < 2) {
            float4* zo = (float4*)(out + (size_t)(seg + 1) * NSAMP * DD + (size_t)n * DD) + q;
            *zo = make_float4(zsh[0], zsh[1], zsh[2], zsh[3]);
        }
        if (q == 0) out[LPBASE + (size_t)(seg + 1) * NSAMP + n] = lp;
    }
}

extern "C" void kernel_launch(void* const* d_in, const int* in_sizes, int n_in,
                              void* d_out, int out_size, void* d_ws, size_t ws_size,
                              hipStream_t stream) {
    const float* ts  = (const float*)d_in[0];
    const float* z0  = (const float*)d_in[1];
    const float* lp0 = (const float*)d_in[2];
    const float* w1  = (const float*)d_in[3];
    const float* b1  = (const float*)d_in[4];
    const float* w2  = (const float*)d_in[5];
    const float* b2  = (const float*)d_in[6];
    const float* w3  = (const float*)d_in[7];
    const float* b3  = (const float*)d_in[8];
    __fp16* params = (__fp16*)d_ws;  // 63 * 8704 B = 548 KB

    cnf_hyper<<<dim3(NSLOT), dim3(256), 0, stream>>>(ts, w1, b1, w2, b2, w3, b3, params);
    cnf_integrate<<<dim3(NSAMP / 64), dim3(256), 0, stream>>>(
        ts, z0, lp0, params, (float*)d_out);
}